// Round 9
// baseline (862.432 us; speedup 1.0000x reference)
//
#include <hip/hip_runtime.h>
#include <stdint.h>

#define NE 500000
#define NN 50000
#define ND 256
#define ED 128
#define GD 64
#define MAXDEG 64

typedef float f4v __attribute__((ext_vector_type(4)));
typedef short s8v __attribute__((ext_vector_type(8)));
typedef short s4v __attribute__((ext_vector_type(4)));

static __device__ __forceinline__ short f2bf(float f) {
  union { float f; uint32_t u; } v; v.f = f;
  uint32_t r = v.u + 0x7FFFu + ((v.u >> 16) & 1u);
  return (short)(r >> 16);
}
static __device__ __forceinline__ float bf2f(uint32_t u) {
  union { uint32_t u; float f; } v; v.u = u << 16; return v.f;
}

// ---- convert fp32 -> bf16 (vectorized x4) ----
__global__ void cvt_bf16_kernel(const float* __restrict__ src, short* __restrict__ dst, int n) {
  int i = (blockIdx.x * blockDim.x + threadIdx.x) * 4;
  if (i >= n) return;
  const float4 v = *(const float4*)(src + i);
  s4v o; o[0] = f2bf(v.x); o[1] = f2bf(v.y); o[2] = f2bf(v.z); o[3] = f2bf(v.w);
  *(s4v*)(dst + i) = o;
}

// ---- pack W[K][C] row-major fp32 -> bf16 MFMA fragment order [ks][c][kh][j] ----
__global__ void pack_w_kernel(const float* __restrict__ src, short* __restrict__ dst, int K, int C) {
  int idx = blockIdx.x * blockDim.x + threadIdx.x;
  if (idx >= K * C) return;
  int k = idx / C, c = idx - k * C;
  int ks = k >> 5, kh = (k >> 3) & 3, j = k & 7;
  dst[(((ks * C + c) * 4 + kh) << 3) + j] = f2bf(src[idx]);
}

// ---- build per-destination lists over raw edge ids ----
__global__ void build_kernel(const int* __restrict__ ecol, unsigned int* __restrict__ cnt,
                             int* __restrict__ elist) {
  int e = blockIdx.x * blockDim.x + threadIdx.x;
  if (e >= NE) return;
  int c = ecol[e];
  unsigned int slot = atomicAdd(&cnt[c], 1u);
  if (slot < MAXDEG) elist[c * MAXDEG + slot] = e;
}

// ---- gather-mean: one wave per node, lane handles 2 dims ----
__global__ void agg_kernel(const unsigned short* __restrict__ ebuf,
                           const int* __restrict__ elist,
                           const unsigned int* __restrict__ cnt,
                           unsigned short* __restrict__ aggbf) {
  int tid = threadIdx.x;
  int lane = tid & 63;
  int node = blockIdx.x * 4 + (tid >> 6);
  if (node >= NN) return;
  unsigned int deg = cnt[node];
  unsigned int jend = deg < MAXDEG ? deg : MAXDEG;
  float a0 = 0.f, a1 = 0.f;
  const int* el = elist + (size_t)node * MAXDEG;
  for (unsigned int j = 0; j < jend; ++j) {
    int eid = el[j];
    uint32_t v = *(const uint32_t*)(ebuf + (size_t)eid * ED + 2 * lane);
    a0 += bf2f(v & 0xFFFFu);
    a1 += bf2f(v >> 16);
  }
  float rc = 1.0f / (deg > 0 ? (float)deg : 1.0f);
  uint32_t o = (uint32_t)(uint16_t)f2bf(a0 * rc) | ((uint32_t)(uint16_t)f2bf(a1 * rc) << 16);
  *(uint32_t*)(aggbf + (size_t)node * ED + 2 * lane) = o;
}

// =======================================================================
// Edge kernel: M=128 edges/WG, 16 waves (1024 thr), operand-swapped MFMA.
// Pipelined staging: A1 staged in three K=128 chunks (32KB buffer); the
// next chunk's global loads are issued BEFORE GEMM1 runs on the current
// chunk (T14 async-split: latency hides under ~4000cyc of MFMA).
// Freed LDS -> full H1 [128][512] (128KB): single-pass GEMM2 K=512.
// LDS total = 32 + 128 = 160KB exactly. Each thread stages exactly one
// A1 row (rid in a register, no LDS rid).
// GEMM1: wave w owns H1 cols [32w, 32w+32): acc1[2][8].
// GEMM2: wave w owns out-cols tile (w&7), edge-half (w>>3): acc2[4].
// =======================================================================
__launch_bounds__(1024, 4)
__global__ void edge_kernel(const short* __restrict__ xbf,
                            const float* __restrict__ edge_attr,
                            const short* __restrict__ w1p,
                            const float* __restrict__ b1,
                            const short* __restrict__ w2p,
                            const float* __restrict__ b2,
                            const int* __restrict__ erow,
                            unsigned short* __restrict__ ebuf) {
  __shared__ __align__(16) short smem[128 * 128 + 128 * 512];  // 32KB chunk + 128KB H1
  short* const a1c = smem;                    // A1 chunk [128][128] (stride 256B), later out tile
  char* const h1b = (char*)(smem + 128 * 128); // H1 [128][512] (stride 1024B)
  const int tid = threadIdx.x;
  const int lane = tid & 63;
  const int w = tid >> 6;          // wave 0..15
  const int lh = lane >> 4;        // 0..3
  const int ll = lane & 15;        // 0..15
  const int e0 = blockIdx.x * 128;

  // ---- per-thread staging assignment: one row, 16 elems (32B) ----
  const int srow = tid >> 3;               // 0..127
  const int scol = (tid & 7) * 16;         // elem col offset within chunk
  const bool okS = (e0 + srow) < NE;
  const int rid_t = okS ? erow[e0 + srow] : 0;
  const int sb0 = (srow * 256 + scol * 2) ^ ((srow & 7) << 4);
  const int sb1 = (srow * 256 + scol * 2 + 16) ^ ((srow & 7) << 4);

  // ---- prefetch chunk0 + chunk1 (xbf cols 0..127, 128..255) ----
  s8v c0a = {0,0,0,0,0,0,0,0}, c0b = c0a, c1a = c0a, c1b = c0a;
  if (okS) {
    const short* px = xbf + (size_t)rid_t * ND;
    c0a = *(const s8v*)(px + scol);
    c0b = *(const s8v*)(px + scol + 8);
    c1a = *(const s8v*)(px + 128 + scol);
    c1b = *(const s8v*)(px + 128 + scol + 8);
  }
  *(s8v*)((char*)a1c + sb0) = c0a;
  *(s8v*)((char*)a1c + sb1) = c0b;
  __syncthreads();                          // chunk0 visible

  f4v acc1[2][8];
  #pragma unroll
  for (int n = 0; n < 2; ++n)
    #pragma unroll
    for (int m = 0; m < 8; ++m)
      acc1[n][m] = (f4v){0.f, 0.f, 0.f, 0.f};

  // ---- GEMM1 chunk macro: 4 ks of K=32 on current chunk ----
  auto gemm1_chunk = [&](int kc) {
    #pragma unroll
    for (int ks = 0; ks < 4; ++ks) {
      int ksg = kc * 4 + ks;
      s8v wf0 = *(const s8v*)(w1p + (((ksg * 512 + 32 * w + ll) * 4 + lh) << 3));
      s8v wf1 = *(const s8v*)(w1p + (((ksg * 512 + 32 * w + 16 + ll) * 4 + lh) << 3));
      #pragma unroll
      for (int m = 0; m < 8; ++m) {
        int row = 16 * m + ll;
        int byte = (row * 256 + ks * 64 + lh * 16) ^ ((row & 7) << 4);
        s8v hf = *(const s8v*)((const char*)a1c + byte);
        acc1[0][m] = __builtin_amdgcn_mfma_f32_16x16x32_bf16(wf0, hf, acc1[0][m], 0, 0, 0);
        acc1[1][m] = __builtin_amdgcn_mfma_f32_16x16x32_bf16(wf1, hf, acc1[1][m], 0, 0, 0);
      }
    }
  };

  gemm1_chunk(0);
  __syncthreads();                          // chunk0 reads done
  *(s8v*)((char*)a1c + sb0) = c1a;
  *(s8v*)((char*)a1c + sb1) = c1b;
  __syncthreads();                          // chunk1 visible

  // ---- issue ea loads (chunk2) now; consumed after chunk1 GEMM ----
  float4 ef0 = {0,0,0,0}, ef1 = ef0, ef2 = ef0, ef3 = ef0;
  if (okS) {
    const float* pe = edge_attr + (size_t)(e0 + srow) * ED + scol;
    ef0 = *(const float4*)(pe);
    ef1 = *(const float4*)(pe + 4);
    ef2 = *(const float4*)(pe + 8);
    ef3 = *(const float4*)(pe + 12);
  }

  gemm1_chunk(1);
  __syncthreads();                          // chunk1 reads done
  {
    s8v ev0, ev1;
    ev0[0] = f2bf(ef0.x); ev0[1] = f2bf(ef0.y); ev0[2] = f2bf(ef0.z); ev0[3] = f2bf(ef0.w);
    ev0[4] = f2bf(ef1.x); ev0[5] = f2bf(ef1.y); ev0[6] = f2bf(ef1.z); ev0[7] = f2bf(ef1.w);
    ev1[0] = f2bf(ef2.x); ev1[1] = f2bf(ef2.y); ev1[2] = f2bf(ef2.z); ev1[3] = f2bf(ef2.w);
    ev1[4] = f2bf(ef3.x); ev1[5] = f2bf(ef3.y); ev1[6] = f2bf(ef3.z); ev1[7] = f2bf(ef3.w);
    *(s8v*)((char*)a1c + sb0) = ev0;
    *(s8v*)((char*)a1c + sb1) = ev1;
  }
  __syncthreads();                          // chunk2 visible
  gemm1_chunk(2);

  // ---- H1 = relu(acc1 + b1) -> LDS [128][512] bf16 swizzled (per-wave, no barrier) ----
  #pragma unroll
  for (int n = 0; n < 2; ++n) {
    int lcb = 32 * w + 16 * n + 4 * lh;
    const float4 bv = *(const float4*)(b1 + lcb);
    #pragma unroll
    for (int m = 0; m < 8; ++m) {
      int row = 16 * m + ll;
      s4v o;
      float v0 = acc1[n][m][0] + bv.x; o[0] = f2bf(v0 > 0.f ? v0 : 0.f);
      float v1 = acc1[n][m][1] + bv.y; o[1] = f2bf(v1 > 0.f ? v1 : 0.f);
      float v2 = acc1[n][m][2] + bv.z; o[2] = f2bf(v2 > 0.f ? v2 : 0.f);
      float v3 = acc1[n][m][3] + bv.w; o[3] = f2bf(v3 > 0.f ? v3 : 0.f);
      int byte = (row * 1024 + lcb * 2) ^ ((row & 7) << 4);
      *(s4v*)(h1b + byte) = o;
    }
  }
  __syncthreads();                          // H1 visible

  // ---- GEMM2 (swapped), full K=512: c2-tile (w&7), edge-half (w>>3) ----
  f4v acc2[4];
  #pragma unroll
  for (int m = 0; m < 4; ++m)
    acc2[m] = (f4v){0.f, 0.f, 0.f, 0.f};

  const int c2b = (w & 7) * 16;
  const int ehb = (w >> 3) * 64;
  for (int ks = 0; ks < 16; ++ks) {
    s8v wf = *(const s8v*)(w2p + (((ks * 128 + c2b + ll) * 4 + lh) << 3));
    #pragma unroll
    for (int m = 0; m < 4; ++m) {
      int row = ehb + 16 * m + ll;
      int byte = (row * 1024 + ks * 64 + lh * 16) ^ ((row & 7) << 4);
      s8v hf = *(const s8v*)(h1b + byte);
      acc2[m] = __builtin_amdgcn_mfma_f32_16x16x32_bf16(wf, hf, acc2[m], 0, 0, 0);
    }
  }
  __syncthreads();                          // H1 reads done; a1c region reusable

  // ---- stage output tile [128][128] bf16 in chunk region (swizzled) ----
  {
    int cb = c2b + 4 * lh;
    const float4 bv = *(const float4*)(b2 + cb);
    #pragma unroll
    for (int m = 0; m < 4; ++m) {
      int row = ehb + 16 * m + ll;
      s4v o;
      o[0] = f2bf(acc2[m][0] + bv.x);
      o[1] = f2bf(acc2[m][1] + bv.y);
      o[2] = f2bf(acc2[m][2] + bv.z);
      o[3] = f2bf(acc2[m][3] + bv.w);
      int byte = (row * 256 + cb * 2) ^ ((row & 7) << 4);
      *(s4v*)((char*)a1c + byte) = o;
    }
  }
  __syncthreads();

  // ---- coalesced store: 1024 threads x 2 x 16B = full 32KB tile ----
  {
    size_t g0 = (size_t)e0 * ED;        // elements
    #pragma unroll
    for (int it = 0; it < 2; ++it) {
      int B = (tid + it * 1024) * 16;   // byte offset in [0,32768)
      int row = B >> 8;
      int lb = B ^ ((row & 7) << 4);
      s8v v = *(const s8v*)((const char*)a1c + lb);
      if (e0 + row < NE)
        *(s8v*)((char*)(ebuf + g0) + B) = v;
    }
  }
}

// =======================================================================
// Node kernel: unchanged (R3 form).
// =======================================================================
__launch_bounds__(512, 2)
__global__ void node_kernel(const float* __restrict__ x,
                            const short* __restrict__ xbf,
                            const float* __restrict__ u,
                            const short* __restrict__ w3p,
                            const float* __restrict__ b3,
                            const short* __restrict__ w4p,
                            const float* __restrict__ b4,
                            const float* __restrict__ gamma,
                            const float* __restrict__ beta,
                            const int* __restrict__ batch,
                            const unsigned short* __restrict__ aggbf,
                            float* __restrict__ out) {
  __shared__ __align__(16) short smem[64 * 1024];
  const int tid = threadIdx.x;
  const int lane = tid & 63;
  const int w = tid >> 6;
  const int lh = lane >> 4;
  const int ll = lane & 15;
  const int n0 = blockIdx.x * 64;

  #pragma unroll
  for (int it = 0; it < 7; ++it) {
    int ch = tid + it * 512;
    int rr = ch / 56;
    int cc = (ch - rr * 56) * 8;
    s8v vals = {0, 0, 0, 0, 0, 0, 0, 0};
    int node = n0 + rr;
    if (node < NN) {
      if (cc < 256) {
        vals = *(const s8v*)(xbf + (size_t)node * ND + cc);
      } else if (cc < 384) {
        vals = *(const s8v*)(aggbf + (size_t)node * ED + (cc - 256));
      } else {
        const float* up = u + (size_t)batch[node] * GD + (cc - 384);
        const float4 v0 = *(const float4*)(up);
        const float4 v1 = *(const float4*)(up + 4);
        vals[0] = f2bf(v0.x); vals[1] = f2bf(v0.y); vals[2] = f2bf(v0.z); vals[3] = f2bf(v0.w);
        vals[4] = f2bf(v1.x); vals[5] = f2bf(v1.y); vals[6] = f2bf(v1.z); vals[7] = f2bf(v1.w);
      }
    }
    int byte = (rr * 896 + cc * 2) ^ ((rr & 7) << 4);
    *(s8v*)((char*)smem + byte) = vals;
  }
  __syncthreads();

  f4v acc3[8][4];
  #pragma unroll
  for (int n = 0; n < 8; ++n)
    #pragma unroll
    for (int m = 0; m < 4; ++m)
      acc3[n][m] = (f4v){0.f, 0.f, 0.f, 0.f};

  for (int ks = 0; ks < 14; ++ks) {
    s8v af[4];
    #pragma unroll
    for (int m = 0; m < 4; ++m) {
      int row = 16 * m + ll;
      int byte = (row * 896 + ks * 64 + lh * 16) ^ ((row & 7) << 4);
      af[m] = *(const s8v*)((const char*)smem + byte);
    }
    #pragma unroll
    for (int n = 0; n < 8; ++n) {
      s8v wf = *(const s8v*)(w3p + (((ks * 1024 + w * 128 + 16 * n + ll) * 4 + lh) << 3));
      #pragma unroll
      for (int m = 0; m < 4; ++m)
        acc3[n][m] = __builtin_amdgcn_mfma_f32_16x16x32_bf16(wf, af[m], acc3[n][m], 0, 0, 0);
    }
  }
  __syncthreads();

  #pragma unroll
  for (int n = 0; n < 8; ++n) {
    int cb = w * 128 + 16 * n + 4 * lh;
    const float4 bv = *(const float4*)(b3 + cb);
    #pragma unroll
    for (int m = 0; m < 4; ++m) {
      int row = 16 * m + ll;
      s4v o;
      float v0 = acc3[n][m][0] + bv.x; o[0] = f2bf(v0 > 0.f ? v0 : 0.f);
      float v1 = acc3[n][m][1] + bv.y; o[1] = f2bf(v1 > 0.f ? v1 : 0.f);
      float v2 = acc3[n][m][2] + bv.z; o[2] = f2bf(v2 > 0.f ? v2 : 0.f);
      float v3 = acc3[n][m][3] + bv.w; o[3] = f2bf(v3 > 0.f ? v3 : 0.f);
      int byte = (row * 2048 + cb * 2) ^ ((row & 7) << 4);
      *(s4v*)((char*)smem + byte) = o;
    }
  }
  __syncthreads();

  f4v acc4[2][4];
  #pragma unroll
  for (int n = 0; n < 2; ++n)
    #pragma unroll
    for (int m = 0; m < 4; ++m)
      acc4[n][m] = (f4v){0.f, 0.f, 0.f, 0.f};

  for (int ks = 0; ks < 32; ++ks) {
    s8v hf[4];
    #pragma unroll
    for (int m = 0; m < 4; ++m) {
      int row = 16 * m + ll;
      int byte = (row * 2048 + ks * 64 + lh * 16) ^ ((row & 7) << 4);
      hf[m] = *(const s8v*)((const char*)smem + byte);
    }
    #pragma unroll
    for (int n = 0; n < 2; ++n) {
      s8v wf = *(const s8v*)(w4p + (((ks * 256 + w * 32 + 16 * n + ll) * 4 + lh) << 3));
      #pragma unroll
      for (int m = 0; m < 4; ++m)
        acc4[n][m] = __builtin_amdgcn_mfma_f32_16x16x32_bf16(wf, hf[m], acc4[n][m], 0, 0, 0);
    }
  }
  __syncthreads();

  float* yb = (float*)smem;
  #pragma unroll
  for (int n = 0; n < 2; ++n) {
    int cb = w * 32 + 16 * n + 4 * lh;
    const float4 bv = *(const float4*)(b4 + cb);
    #pragma unroll
    for (int m = 0; m < 4; ++m) {
      int row = 16 * m + ll;
      int node = n0 + row;
      float4 xv = {0.f, 0.f, 0.f, 0.f};
      if (node < NN) xv = *(const float4*)(x + (size_t)node * ND + cb);
      f4v o;
      o[0] = acc4[n][m][0] + bv.x + xv.x;
      o[1] = acc4[n][m][1] + bv.y + xv.y;
      o[2] = acc4[n][m][2] + bv.z + xv.z;
      o[3] = acc4[n][m][3] + bv.w + xv.w;
      *(f4v*)(yb + row * 260 + cb) = o;
    }
  }
  __syncthreads();

  {
    int row = tid >> 3, sub = tid & 7;
    int node = n0 + row;
    float v[32];
    float sum = 0.f, ssq = 0.f;
    #pragma unroll
    for (int i = 0; i < 8; ++i) {
      const float4 t = *(const float4*)(yb + row * 260 + (i * 8 + sub) * 4);
      v[i * 4 + 0] = t.x; v[i * 4 + 1] = t.y; v[i * 4 + 2] = t.z; v[i * 4 + 3] = t.w;
      sum += t.x + t.y + t.z + t.w;
      ssq += t.x * t.x + t.y * t.y + t.z * t.z + t.w * t.w;
    }
    #pragma unroll
    for (int d = 1; d < 8; d <<= 1) {
      sum += __shfl_xor(sum, d);
      ssq += __shfl_xor(ssq, d);
    }
    float mu = sum * (1.f / 256.f);
    float var = ssq * (1.f / 256.f) - mu * mu;
    float rstd = rsqrtf(var + 1e-5f);
    if (node < NN) {
      #pragma unroll
      for (int i = 0; i < 8; ++i) {
        int c = (i * 8 + sub) * 4;
        const float4 g = *(const float4*)(gamma + c);
        const float4 be = *(const float4*)(beta + c);
        float4 o;
        o.x = (v[i * 4 + 0] - mu) * rstd * g.x + be.x;
        o.y = (v[i * 4 + 1] - mu) * rstd * g.y + be.y;
        o.z = (v[i * 4 + 2] - mu) * rstd * g.z + be.z;
        o.w = (v[i * 4 + 3] - mu) * rstd * g.w + be.w;
        *(float4*)(out + (size_t)node * ND + c) = o;
      }
    }
  }
}

extern "C" void kernel_launch(void* const* d_in, const int* in_sizes, int n_in,
                              void* d_out, int out_size, void* d_ws, size_t ws_size,
                              hipStream_t stream) {
  const float* x    = (const float*)d_in[0];
  const float* ea   = (const float*)d_in[1];
  const float* u    = (const float*)d_in[2];
  const float* W1   = (const float*)d_in[3];
  const float* b1   = (const float*)d_in[4];
  const float* W2   = (const float*)d_in[5];
  const float* b2   = (const float*)d_in[6];
  const float* W3   = (const float*)d_in[7];
  const float* b3   = (const float*)d_in[8];
  const float* W4   = (const float*)d_in[9];
  const float* b4   = (const float*)d_in[10];
  const float* gamma = (const float*)d_in[11];
  const float* beta  = (const float*)d_in[12];
  const int* eidx   = (const int*)d_in[13];
  const int* batch  = (const int*)d_in[14];
  float* out = (float*)d_out;

  char* p = (char*)d_ws;
  size_t off = 0;
  auto take = [&](size_t n) { char* r = p + off; off = (off + n + 255) & ~(size_t)255; return r; };
  short* xbf = (short*)take((size_t)NN * ND * 2);
  short* w1p = (short*)take((size_t)384 * 512 * 2);
  short* w2p = (short*)take((size_t)512 * 128 * 2);
  short* w3p = (short*)take((size_t)448 * 1024 * 2);
  short* w4p = (short*)take((size_t)1024 * 256 * 2);
  unsigned int* cnt = (unsigned int*)take((size_t)NN * 4);
  int* elist = (int*)take((size_t)NN * MAXDEG * 4);
  unsigned short* aggbf = (unsigned short*)take((size_t)NN * ED * 2);
  unsigned short* ebuf = (unsigned short*)take((size_t)NE * ED * 2);

  const int* erow = eidx;
  const int* ecol = eidx + NE;

  cvt_bf16_kernel<<<(NN * ND / 4 + 255) / 256, 256, 0, stream>>>(x, xbf, NN * ND);
  pack_w_kernel<<<(384 * 512 + 255) / 256, 256, 0, stream>>>(W1, w1p, 384, 512);
  pack_w_kernel<<<(512 * 128 + 255) / 256, 256, 0, stream>>>(W2, w2p, 512, 128);
  pack_w_kernel<<<(448 * 1024 + 255) / 256, 256, 0, stream>>>(W3, w3p, 448, 1024);
  pack_w_kernel<<<(1024 * 256 + 255) / 256, 256, 0, stream>>>(W4, w4p, 1024, 256);
  hipMemsetAsync(cnt, 0, (size_t)NN * 4, stream);
  build_kernel<<<(NE + 255) / 256, 256, 0, stream>>>(ecol, cnt, elist);

  edge_kernel<<<(NE + 127) / 128, 1024, 0, stream>>>(xbf, ea, w1p, b1, w2p, b2, erow, ebuf);
  agg_kernel<<<(NN + 3) / 4, 256, 0, stream>>>(ebuf, elist, cnt, aggbf);
  node_kernel<<<(NN + 63) / 64, 512, 0, stream>>>(x, xbf, u, w3p, b3, w4p, b4,
                                                  gamma, beta, batch, aggbf, out);
}

// Round 10
// 725.403 us; speedup vs baseline: 1.1889x; 1.1889x over previous
//
#include <hip/hip_runtime.h>
#include <stdint.h>

#define NE 500000
#define NN 50000
#define ND 256
#define ED 128
#define GD 64
#define MAXDEG 64

typedef float f4v __attribute__((ext_vector_type(4)));
typedef short s8v __attribute__((ext_vector_type(8)));
typedef short s4v __attribute__((ext_vector_type(4)));

static __device__ __forceinline__ short f2bf(float f) {
  union { float f; uint32_t u; } v; v.f = f;
  uint32_t r = v.u + 0x7FFFu + ((v.u >> 16) & 1u);
  return (short)(r >> 16);
}
static __device__ __forceinline__ float bf2f(uint32_t u) {
  union { uint32_t u; float f; } v; v.u = u << 16; return v.f;
}

// ---- convert fp32 -> bf16 (vectorized x4) ----
__global__ void cvt_bf16_kernel(const float* __restrict__ src, short* __restrict__ dst, int n) {
  int i = (blockIdx.x * blockDim.x + threadIdx.x) * 4;
  if (i >= n) return;
  const float4 v = *(const float4*)(src + i);
  s4v o; o[0] = f2bf(v.x); o[1] = f2bf(v.y); o[2] = f2bf(v.z); o[3] = f2bf(v.w);
  *(s4v*)(dst + i) = o;
}

// ---- pack W[K][C] row-major fp32 -> bf16 MFMA fragment order [ks][c][kh][j] ----
__global__ void pack_w_kernel(const float* __restrict__ src, short* __restrict__ dst, int K, int C) {
  int idx = blockIdx.x * blockDim.x + threadIdx.x;
  if (idx >= K * C) return;
  int k = idx / C, c = idx - k * C;
  int ks = k >> 5, kh = (k >> 3) & 3, j = k & 7;
  dst[(((ks * C + c) * 4 + kh) << 3) + j] = f2bf(src[idx]);
}

// ---- build per-destination lists over raw edge ids ----
__global__ void build_kernel(const int* __restrict__ ecol, unsigned int* __restrict__ cnt,
                             int* __restrict__ elist) {
  int e = blockIdx.x * blockDim.x + threadIdx.x;
  if (e >= NE) return;
  int c = ecol[e];
  unsigned int slot = atomicAdd(&cnt[c], 1u);
  if (slot < MAXDEG) elist[c * MAXDEG + slot] = e;
}

// ---- gather-mean: one wave per node, lane handles 2 dims ----
__global__ void agg_kernel(const unsigned short* __restrict__ ebuf,
                           const int* __restrict__ elist,
                           const unsigned int* __restrict__ cnt,
                           unsigned short* __restrict__ aggbf) {
  int tid = threadIdx.x;
  int lane = tid & 63;
  int node = blockIdx.x * 4 + (tid >> 6);
  if (node >= NN) return;
  unsigned int deg = cnt[node];
  unsigned int jend = deg < MAXDEG ? deg : MAXDEG;
  float a0 = 0.f, a1 = 0.f;
  const int* el = elist + (size_t)node * MAXDEG;
  for (unsigned int j = 0; j < jend; ++j) {
    int eid = el[j];
    uint32_t v = *(const uint32_t*)(ebuf + (size_t)eid * ED + 2 * lane);
    a0 += bf2f(v & 0xFFFFu);
    a1 += bf2f(v >> 16);
  }
  float rc = 1.0f / (deg > 0 ? (float)deg : 1.0f);
  uint32_t o = (uint32_t)(uint16_t)f2bf(a0 * rc) | ((uint32_t)(uint16_t)f2bf(a1 * rc) << 16);
  *(uint32_t*)(aggbf + (size_t)node * ED + 2 * lane) = o;
}

// =======================================================================
// Edge kernel: EXACT R8-benched version (456us, WRITE=125MB, no spill).
// M=128 edges/WG, 16 waves. A1 [128][384] 96KB + H1-half [128][256] 64KB
// = 160KB. GEMM1: wave w -> col-tile w (half0) + 16+w (half1); GEMM2 as
// two K=256 passes. Coalesced full-line output store.
// NOTE: R9's reg-prefetch pipeline variant SPILLED (64 AGPR acc + 32 VGPR
// held loads > 128-reg budget at 4 waves/SIMD) -> +560MB scratch WRITE.
// Do not re-introduce cross-phase register staging here.
// =======================================================================
__launch_bounds__(1024, 4)
__global__ void edge_kernel(const short* __restrict__ xbf,
                            const float* __restrict__ edge_attr,
                            const short* __restrict__ w1p,
                            const float* __restrict__ b1,
                            const short* __restrict__ w2p,
                            const float* __restrict__ b2,
                            const int* __restrict__ erow,
                            unsigned short* __restrict__ ebuf) {
  __shared__ __align__(16) short smem[128 * 384 + 128 * 256];  // 96KB + 64KB
  char* const h1b = (char*)smem + 128 * 384 * 2;               // H1 half region
  int* const rid = (int*)h1b;                                  // transient: dead before H1 writes
  const int tid = threadIdx.x;
  const int lane = tid & 63;
  const int w = tid >> 6;          // wave 0..15
  const int lh = lane >> 4;        // 0..3
  const int ll = lane & 15;        // 0..15
  const int e0 = blockIdx.x * 128;

  if (tid < 128) {
    int e = e0 + tid;
    rid[tid] = (e < NE) ? erow[e] : 0;
  }
  __syncthreads();

  // ---- stage A1 [128][384] bf16, XOR-swizzled rows (6 iters) ----
  #pragma unroll
  for (int it = 0; it < 6; ++it) {
    int ch = tid + it * 1024;            // 6144 chunks of 8 elems
    int rr = ch / 48;
    int cc = (ch - rr * 48) * 8;
    s8v vals = {0, 0, 0, 0, 0, 0, 0, 0};
    if (e0 + rr < NE) {
      if (cc < ND) {
        vals = *(const s8v*)(xbf + (size_t)rid[rr] * ND + cc);
      } else {
        const float* p = edge_attr + (size_t)(e0 + rr) * ED + (cc - ND);
        const float4 v0 = *(const float4*)(p);
        const float4 v1 = *(const float4*)(p + 4);
        vals[0] = f2bf(v0.x); vals[1] = f2bf(v0.y); vals[2] = f2bf(v0.z); vals[3] = f2bf(v0.w);
        vals[4] = f2bf(v1.x); vals[5] = f2bf(v1.y); vals[6] = f2bf(v1.z); vals[7] = f2bf(v1.w);
      }
    }
    int byte = (rr * 768 + cc * 2) ^ ((rr & 7) << 4);
    *(s8v*)((char*)smem + byte) = vals;
  }
  __syncthreads();

  // ---- GEMM1 (swapped): acc1[n][mt]; n=0 -> col-tile w (cols 16w),
  //      n=1 -> col-tile 16+w (cols 256+16w); mt = edge-tile 0..7 ----
  f4v acc1[2][8];
  #pragma unroll
  for (int n = 0; n < 2; ++n)
    #pragma unroll
    for (int m = 0; m < 8; ++m)
      acc1[n][m] = (f4v){0.f, 0.f, 0.f, 0.f};

  for (int ks = 0; ks < 12; ++ks) {
    s8v wf0 = *(const s8v*)(w1p + (((ks * 512 + w * 16 + ll) * 4 + lh) << 3));
    s8v wf1 = *(const s8v*)(w1p + (((ks * 512 + 256 + w * 16 + ll) * 4 + lh) << 3));
    #pragma unroll
    for (int mh = 0; mh < 2; ++mh) {
      s8v hf[4];
      #pragma unroll
      for (int m = 0; m < 4; ++m) {
        int row = 64 * mh + 16 * m + ll;
        int byte = (row * 768 + ks * 64 + lh * 16) ^ ((row & 7) << 4);
        hf[m] = *(const s8v*)((const char*)smem + byte);
      }
      #pragma unroll
      for (int m = 0; m < 4; ++m) {
        acc1[0][4 * mh + m] = __builtin_amdgcn_mfma_f32_16x16x32_bf16(wf0, hf[m], acc1[0][4 * mh + m], 0, 0, 0);
        acc1[1][4 * mh + m] = __builtin_amdgcn_mfma_f32_16x16x32_bf16(wf1, hf[m], acc1[1][4 * mh + m], 0, 0, 0);
      }
    }
  }
  __syncthreads();   // A1 reads done for GEMM1; rid dead from here

  // ---- GEMM2 accumulators: c2-tile (w&7), edge-quarter (w>>3) ----
  f4v acc2[4];
  #pragma unroll
  for (int m = 0; m < 4; ++m)
    acc2[m] = (f4v){0.f, 0.f, 0.f, 0.f};

  // ---- two half passes over H1 cols: write half -> GEMM2 K=256 ----
  #pragma unroll
  for (int half = 0; half < 2; ++half) {
    // write H1 half: wave w writes its col-tile (local cols 16w+4lh..+3)
    {
      int lcb = w * 16 + 4 * lh;                    // local col in [0,256)
      const float4 bv = *(const float4*)(b1 + half * 256 + lcb);
      #pragma unroll
      for (int m = 0; m < 8; ++m) {
        int row = 16 * m + ll;
        s4v o;
        float v0 = acc1[half][m][0] + bv.x; o[0] = f2bf(v0 > 0.f ? v0 : 0.f);
        float v1 = acc1[half][m][1] + bv.y; o[1] = f2bf(v1 > 0.f ? v1 : 0.f);
        float v2 = acc1[half][m][2] + bv.z; o[2] = f2bf(v2 > 0.f ? v2 : 0.f);
        float v3 = acc1[half][m][3] + bv.w; o[3] = f2bf(v3 > 0.f ? v3 : 0.f);
        int byte = (row * 512 + lcb * 2) ^ ((row & 7) << 4);
        *(s4v*)(h1b + byte) = o;
      }
    }
    __syncthreads();   // H1 half visible

    // GEMM2 partial: K = 256 (8 ks)
    for (int ksl = 0; ksl < 8; ++ksl) {
      int ksg = half * 8 + ksl;
      s8v wf = *(const s8v*)(w2p + (((ksg * 128 + (w & 7) * 16 + ll) * 4 + lh) << 3));
      #pragma unroll
      for (int m = 0; m < 4; ++m) {
        int row = 64 * (w >> 3) + 16 * m + ll;
        int byte = (row * 512 + ksl * 64 + lh * 16) ^ ((row & 7) << 4);
        s8v hf = *(const s8v*)(h1b + byte);
        acc2[m] = __builtin_amdgcn_mfma_f32_16x16x32_bf16(wf, hf, acc2[m], 0, 0, 0);
      }
    }
    __syncthreads();   // all GEMM2 reads of this half done before overwrite
  }

  // ---- stage output tile [128][128] bf16 in A1 region (swizzled) ----
  {
    int cb = (w & 7) * 16 + 4 * lh;
    const float4 bv = *(const float4*)(b2 + cb);
    #pragma unroll
    for (int m = 0; m < 4; ++m) {
      int row = 64 * (w >> 3) + 16 * m + ll;
      s4v o;
      o[0] = f2bf(acc2[m][0] + bv.x);
      o[1] = f2bf(acc2[m][1] + bv.y);
      o[2] = f2bf(acc2[m][2] + bv.z);
      o[3] = f2bf(acc2[m][3] + bv.w);
      int byte = (row * 256 + cb * 2) ^ ((row & 7) << 4);
      *(s4v*)((char*)smem + byte) = o;
    }
  }
  __syncthreads();

  // ---- coalesced store: 1024 threads x 2 x 16B = full 32KB tile ----
  {
    size_t g0 = (size_t)e0 * ED;        // elements
    #pragma unroll
    for (int it = 0; it < 2; ++it) {
      int B = (tid + it * 1024) * 16;   // byte offset in [0,32768)
      int row = B >> 8;
      int lb = B ^ ((row & 7) << 4);
      s8v v = *(const s8v*)((const char*)smem + lb);
      if (e0 + row < NE)
        *(s8v*)((char*)(ebuf + g0) + B) = v;
    }
  }
}

// =======================================================================
// Node kernel: 64 nodes/WG, now 16 waves (1024 thr) — was 8 waves at
// 2 waves/SIMD (latency-bound). Same LDS (128KB), same math; wave work
// halved: GEMM3 wave w -> cols [w*64,+64) acc3[4][4]; GEMM4 wave w ->
// cols [w*16,+16) acc4[4]. LN: 16 threads/row.
// =======================================================================
__launch_bounds__(1024, 4)
__global__ void node_kernel(const float* __restrict__ x,
                            const short* __restrict__ xbf,
                            const float* __restrict__ u,
                            const short* __restrict__ w3p,
                            const float* __restrict__ b3,
                            const short* __restrict__ w4p,
                            const float* __restrict__ b4,
                            const float* __restrict__ gamma,
                            const float* __restrict__ beta,
                            const int* __restrict__ batch,
                            const unsigned short* __restrict__ aggbf,
                            float* __restrict__ out) {
  __shared__ __align__(16) short smem[64 * 1024];
  const int tid = threadIdx.x;
  const int lane = tid & 63;
  const int w = tid >> 6;          // wave 0..15
  const int lh = lane >> 4;
  const int ll = lane & 15;
  const int n0 = blockIdx.x * 64;

  // ---- stage A3 [64][448] bf16 swizzled (3584 chunks over 1024 thr) ----
  #pragma unroll
  for (int it = 0; it < 4; ++it) {
    int ch = tid + it * 1024;
    if (ch < 3584) {
      int rr = ch / 56;
      int cc = (ch - rr * 56) * 8;
      s8v vals = {0, 0, 0, 0, 0, 0, 0, 0};
      int node = n0 + rr;
      if (node < NN) {
        if (cc < 256) {
          vals = *(const s8v*)(xbf + (size_t)node * ND + cc);
        } else if (cc < 384) {
          vals = *(const s8v*)(aggbf + (size_t)node * ED + (cc - 256));
        } else {
          const float* up = u + (size_t)batch[node] * GD + (cc - 384);
          const float4 v0 = *(const float4*)(up);
          const float4 v1 = *(const float4*)(up + 4);
          vals[0] = f2bf(v0.x); vals[1] = f2bf(v0.y); vals[2] = f2bf(v0.z); vals[3] = f2bf(v0.w);
          vals[4] = f2bf(v1.x); vals[5] = f2bf(v1.y); vals[6] = f2bf(v1.z); vals[7] = f2bf(v1.w);
        }
      }
      int byte = (rr * 896 + cc * 2) ^ ((rr & 7) << 4);
      *(s8v*)((char*)smem + byte) = vals;
    }
  }
  __syncthreads();

  // ---- GEMM3 (swapped): wave w -> cols [w*64,+64), K=448 ----
  f4v acc3[4][4];
  #pragma unroll
  for (int n = 0; n < 4; ++n)
    #pragma unroll
    for (int m = 0; m < 4; ++m)
      acc3[n][m] = (f4v){0.f, 0.f, 0.f, 0.f};

  for (int ks = 0; ks < 14; ++ks) {
    s8v af[4];
    #pragma unroll
    for (int m = 0; m < 4; ++m) {
      int row = 16 * m + ll;
      int byte = (row * 896 + ks * 64 + lh * 16) ^ ((row & 7) << 4);
      af[m] = *(const s8v*)((const char*)smem + byte);
    }
    #pragma unroll
    for (int n = 0; n < 4; ++n) {
      s8v wf = *(const s8v*)(w3p + (((ks * 1024 + w * 64 + 16 * n + ll) * 4 + lh) << 3));
      #pragma unroll
      for (int m = 0; m < 4; ++m)
        acc3[n][m] = __builtin_amdgcn_mfma_f32_16x16x32_bf16(wf, af[m], acc3[n][m], 0, 0, 0);
    }
  }
  __syncthreads();

  // ---- H3 = relu(acc3 + b3) -> LDS [64][1024] bf16 swizzled ----
  #pragma unroll
  for (int n = 0; n < 4; ++n) {
    int cb = w * 64 + 16 * n + 4 * lh;
    const float4 bv = *(const float4*)(b3 + cb);
    #pragma unroll
    for (int m = 0; m < 4; ++m) {
      int row = 16 * m + ll;
      s4v o;
      float v0 = acc3[n][m][0] + bv.x; o[0] = f2bf(v0 > 0.f ? v0 : 0.f);
      float v1 = acc3[n][m][1] + bv.y; o[1] = f2bf(v1 > 0.f ? v1 : 0.f);
      float v2 = acc3[n][m][2] + bv.z; o[2] = f2bf(v2 > 0.f ? v2 : 0.f);
      float v3 = acc3[n][m][3] + bv.w; o[3] = f2bf(v3 > 0.f ? v3 : 0.f);
      int byte = (row * 2048 + cb * 2) ^ ((row & 7) << 4);
      *(s4v*)((char*)smem + byte) = o;
    }
  }
  __syncthreads();

  // ---- GEMM4 (swapped): wave w -> cols [w*16,+16), K=1024 ----
  f4v acc4[4];
  #pragma unroll
  for (int m = 0; m < 4; ++m)
    acc4[m] = (f4v){0.f, 0.f, 0.f, 0.f};

  for (int ks = 0; ks < 32; ++ks) {
    s8v wf = *(const s8v*)(w4p + (((ks * 256 + w * 16 + ll) * 4 + lh) << 3));
    #pragma unroll
    for (int m = 0; m < 4; ++m) {
      int row = 16 * m + ll;
      int byte = (row * 2048 + ks * 64 + lh * 16) ^ ((row & 7) << 4);
      s8v hf = *(const s8v*)((const char*)smem + byte);
      acc4[m] = __builtin_amdgcn_mfma_f32_16x16x32_bf16(wf, hf, acc4[m], 0, 0, 0);
    }
  }
  __syncthreads();   // all reads of H3 done; re-alias smem as y

  // ---- y = h + b4 + x -> LDS fp32 [64][260] ----
  float* yb = (float*)smem;
  {
    int cb = w * 16 + 4 * lh;
    const float4 bv = *(const float4*)(b4 + cb);
    #pragma unroll
    for (int m = 0; m < 4; ++m) {
      int row = 16 * m + ll;
      int node = n0 + row;
      float4 xv = {0.f, 0.f, 0.f, 0.f};
      if (node < NN) xv = *(const float4*)(x + (size_t)node * ND + cb);
      f4v o;
      o[0] = acc4[m][0] + bv.x + xv.x;
      o[1] = acc4[m][1] + bv.y + xv.y;
      o[2] = acc4[m][2] + bv.z + xv.z;
      o[3] = acc4[m][3] + bv.w + xv.w;
      *(f4v*)(yb + row * 260 + cb) = o;
    }
  }
  __syncthreads();

  // ---- LayerNorm: 16 threads per row ----
  {
    int row = tid >> 4, sub = tid & 15;
    int node = n0 + row;
    float v[16];
    float sum = 0.f, ssq = 0.f;
    #pragma unroll
    for (int i = 0; i < 4; ++i) {
      const float4 t = *(const float4*)(yb + row * 260 + (i * 16 + sub) * 4);
      v[i * 4 + 0] = t.x; v[i * 4 + 1] = t.y; v[i * 4 + 2] = t.z; v[i * 4 + 3] = t.w;
      sum += t.x + t.y + t.z + t.w;
      ssq += t.x * t.x + t.y * t.y + t.z * t.z + t.w * t.w;
    }
    #pragma unroll
    for (int d = 1; d < 16; d <<= 1) {
      sum += __shfl_xor(sum, d);
      ssq += __shfl_xor(ssq, d);
    }
    float mu = sum * (1.f / 256.f);
    float var = ssq * (1.f / 256.f) - mu * mu;
    float rstd = rsqrtf(var + 1e-5f);
    if (node < NN) {
      #pragma unroll
      for (int i = 0; i < 4; ++i) {
        int c = (i * 16 + sub) * 4;
        const float4 g = *(const float4*)(gamma + c);
        const float4 be = *(const float4*)(beta + c);
        float4 o;
        o.x = (v[i * 4 + 0] - mu) * rstd * g.x + be.x;
        o.y = (v[i * 4 + 1] - mu) * rstd * g.y + be.y;
        o.z = (v[i * 4 + 2] - mu) * rstd * g.z + be.z;
        o.w = (v[i * 4 + 3] - mu) * rstd * g.w + be.w;
        *(float4*)(out + (size_t)node * ND + c) = o;
      }
    }
  }
}

extern "C" void kernel_launch(void* const* d_in, const int* in_sizes, int n_in,
                              void* d_out, int out_size, void* d_ws, size_t ws_size,
                              hipStream_t stream) {
  const float* x    = (const float*)d_in[0];
  const float* ea   = (const float*)d_in[1];
  const float* u    = (const float*)d_in[2];
  const float* W1   = (const float*)d_in[3];
  const float* b1   = (const float*)d_in[4];
  const float* W2   = (const float*)d_in[5];
  const float* b2   = (const float*)d_in[6];
  const float* W3   = (const float*)d_in[7];
  const float* b3   = (const float*)d_in[8];
  const float* W4   = (const float*)d_in[9];
  const float* b4   = (const float*)d_in[10];
  const float* gamma = (const float*)d_in[11];
  const float* beta  = (const float*)d_in[12];
  const int* eidx   = (const int*)d_in[13];
  const int* batch  = (const int*)d_in[14];
  float* out = (float*)d_out;

  char* p = (char*)d_ws;
  size_t off = 0;
  auto take = [&](size_t n) { char* r = p + off; off = (off + n + 255) & ~(size_t)255; return r; };
  short* xbf = (short*)take((size_t)NN * ND * 2);
  short* w1p = (short*)take((size_t)384 * 512 * 2);
  short* w2p = (short*)take((size_t)512 * 128 * 2);
  short* w3p = (short*)take((size_t)448 * 1024 * 2);
  short* w4p = (short*)take((size_t)1024 * 256 * 2);
  unsigned int* cnt = (unsigned int*)take((size_t)NN * 4);
  int* elist = (int*)take((size_t)NN * MAXDEG * 4);
  unsigned short* aggbf = (unsigned short*)take((size_t)NN * ED * 2);
  unsigned short* ebuf = (unsigned short*)take((size_t)NE * ED * 2);

  const int* erow = eidx;
  const int* ecol = eidx + NE;

  cvt_bf16_kernel<<<(NN * ND / 4 + 255) / 256, 256, 0, stream>>>(x, xbf, NN * ND);
  pack_w_kernel<<<(384 * 512 + 255) / 256, 256, 0, stream>>>(W1, w1p, 384, 512);
  pack_w_kernel<<<(512 * 128 + 255) / 256, 256, 0, stream>>>(W2, w2p, 512, 128);
  pack_w_kernel<<<(448 * 1024 + 255) / 256, 256, 0, stream>>>(W3, w3p, 448, 1024);
  pack_w_kernel<<<(1024 * 256 + 255) / 256, 256, 0, stream>>>(W4, w4p, 1024, 256);
  hipMemsetAsync(cnt, 0, (size_t)NN * 4, stream);
  build_kernel<<<(NE + 255) / 256, 256, 0, stream>>>(ecol, cnt, elist);

  edge_kernel<<<(NE + 127) / 128, 1024, 0, stream>>>(xbf, ea, w1p, b1, w2p, b2, erow, ebuf);
  agg_kernel<<<(NN + 3) / 4, 256, 0, stream>>>(ebuf, elist, cnt, aggbf);
  node_kernel<<<(NN + 63) / 64, 1024, 0, stream>>>(x, xbf, u, w3p, b3, w4p, b4,
                                                   gamma, beta, batch, aggbf, out);
}